// Round 8
// baseline (3201.693 us; speedup 1.0000x reference)
//
#include <hip/hip_runtime.h>

#define SLEN 512
#define BATCH 64
#define HID 256
#define EMB 128
#define NT 18
#define BQ 8              // batches per group
#define NGROUP 16         // 2 dirs x 8 batch-chunks
#define NSLICE 16         // producer WGs per group (16 units each)
#define FB 8              // batches per feats block
#define SB 4              // timesteps per feats block

typedef unsigned int u32;

__device__ __forceinline__ float sigmoidf_(float v) { return 1.0f / (1.0f + expf(-v)); }

// ---------------------------------------------------------------------------
// Persistent bidirectional LSTM. grid = 256 blocks x 512 threads (1 block/CU,
// all co-resident). group g = blockIdx&15 : dir = g>>3, chunk = g&7 (8 batch).
// slice rk = blockIdx>>4 (0..15): hidden units [16rk,16rk+16) -> 64 gate rows.
// Thread (kg = tid>>6, r = tid&63): row r of slice, K-slice kg (32 h-k's +
// 16 emb-k's). Weights in VGPRs (12 float4/thread). Within a wave kg is
// uniform -> every LDS v-read is a same-address broadcast (conflict-free).
//
// Exchange protocol per step (counter flag, round-4 lineage):
//   wave0: gates -> h stores (relaxed AGENT, write-through) -> vmcnt(0)
//          -> atomic_add(cnt[g][it], 1).
//   all waves at step it+1: poll cnt[g][it] == 16 (one word, one line),
//          then burst-fetch h (bypass loads, exactly once).
// WAR safety: vh/vemb restaged only after SYNC_B(it-1) (barrier ordering);
// red written only after poll(it-1) detect, which implies OUR wave0 finished
// its red reads (our own +1 is part of the 16).
// ---------------------------------------------------------------------------
__global__ __launch_bounds__(512, 1) void lstm_kernel(
    const int* __restrict__ x, const float* __restrict__ embed,
    const float* __restrict__ Wih_f, const float* __restrict__ Whh_f,
    const float* __restrict__ bih_f, const float* __restrict__ bhh_f,
    const float* __restrict__ Wih_b, const float* __restrict__ Whh_b,
    const float* __restrict__ bih_b, const float* __restrict__ bhh_b,
    const float* __restrict__ h0, const float* __restrict__ c0,
    float* __restrict__ h_hist, u32* __restrict__ cnt)
{
  const int g   = blockIdx.x & 15;
  const int rk  = blockIdx.x >> 4;   // 0..15
  const int dir = g >> 3;
  const int b0  = (g & 7) * BQ;
  const int tid = threadIdx.x;       // 0..511
  const int kg  = tid >> 6;          // 0..7  (wave id == K-group)
  const int r   = tid & 63;          // row within the 64 gate rows
  const int gi  = r >> 4;            // gate: 0=i 1=f 2=g 3=o
  const int uo  = r & 15;            // unit offset within slice
  const int grow = gi * 256 + rk * 16 + uo;

  const float* Wih = dir ? Wih_b : Wih_f;
  const float* Whh = dir ? Whh_b : Whh_f;
  const float* bih = dir ? bih_b : bih_f;
  const float* bhh = dir ? bhh_b : bhh_f;

  // weights: c 0..7 -> Whh[grow][32kg+4c] ; c 8..11 -> Wih[grow][16kg+4(c-8)]
  float4 wreg[12];
#pragma unroll
  for (int c = 0; c < 8; ++c)
    wreg[c] = *(const float4*)(Whh + (size_t)grow * 256 + kg * 32 + c * 4);
#pragma unroll
  for (int c = 0; c < 4; ++c)
    wreg[8 + c] = *(const float4*)(Wih + (size_t)grow * 128 + kg * 16 + c * 4);

  __shared__ float vh[BQ][HID];                    // 8 KB   h(t-1)
  __shared__ float vemb[BQ][EMB];                  // 4 KB   emb(t)
  __shared__ __align__(16) float redl[4096];       // 16 KB  [kg][b][u][gate]
  __shared__ float cst[BQ][16];                    // cell state
  __shared__ __align__(16) float biasf[16][4];     // [u][gate]

  if (tid < 64)  biasf[uo][gi] = bih[grow] + bhh[grow];
  if (tid < 128) {
    int b = tid >> 4, u = tid & 15;
    cst[b][u] = c0[(size_t)(dir * BATCH + b0 + b) * HID + rk * 16 + u];
  }
  __syncthreads();

  const int b1 = tid >> 6;           // batch this thread stages emb for
  const int e1 = (tid & 63) * 2;     // emb element offset (float2)
  u32* const vhw = (u32*)&vh[0][0];

  // prologue: emb(0) into ev, x(1) into xv
  float2 ev = *(const float2*)(embed +
               (size_t)x[(b0 + b1) * SLEN + (dir ? SLEN - 1 : 0)] * EMB + e1);
  int xv = x[(b0 + b1) * SLEN + (dir ? SLEN - 2 : 1)];

  for (int it = 0; it < SLEN; ++it) {
    const int t = dir ? (SLEN - 1 - it) : it;

    // ---- 1. stage emb(t) (WAR-safe: all waves passed SYNC_B(it-1)) -------
    *(float2*)&vemb[b1][e1] = ev;

    // ---- 2. poll previous step's counter (one word) ----------------------
    if (it > 0) {
      u32* cp = cnt + (size_t)g * SLEN + (it - 1);
      u32 v = __hip_atomic_load(cp, __ATOMIC_RELAXED, __HIP_MEMORY_SCOPE_AGENT);
      int sp = 0;
      while (v < NSLICE && ++sp < (1 << 16)) {
        __builtin_amdgcn_s_sleep(1);
        v = __hip_atomic_load(cp, __ATOMIC_RELAXED, __HIP_MEMORY_SCOPE_AGENT);
      }
    }
    asm volatile("" ::: "memory");

    // ---- 3. burst-fetch h(t-1) (bypass loads, exactly once) --------------
    u32 hw[4];
    if (it == 0) {
      const u32* hs = (const u32*)(h0 + (size_t)(dir * BATCH + b0) * HID);
#pragma unroll
      for (int i = 0; i < 4; ++i) hw[i] = hs[tid + i * 512];
    } else {
      const int tp = dir ? (t + 1) : (t - 1);
      const u32* hs = (const u32*)(h_hist +
                       ((size_t)(dir * SLEN + tp) * BATCH + b0) * HID);
#pragma unroll
      for (int i = 0; i < 4; ++i)
        hw[i] = __hip_atomic_load((u32*)(hs + tid + i * 512),
                                  __ATOMIC_RELAXED, __HIP_MEMORY_SCOPE_AGENT);
    }
#pragma unroll
    for (int i = 0; i < 4; ++i) vhw[tid + i * 512] = hw[i];
    __syncthreads();                                   // SYNC_A

    // ---- 4. GEMM (h part), prefetch next emb/x, GEMM (emb part) ----------
    float acc[BQ];
#pragma unroll
    for (int b = 0; b < BQ; ++b) acc[b] = 0.0f;
    const int khb = kg * 32;
#pragma unroll
    for (int c = 0; c < 8; ++c) {
      float4 w4 = wreg[c];
#pragma unroll
      for (int q = 0; q < BQ; ++q) {
        float4 v4 = *(const float4*)&vh[q][khb + c * 4];   // broadcast read
        acc[q] = fmaf(w4.x, v4.x, acc[q]);
        acc[q] = fmaf(w4.y, v4.y, acc[q]);
        acc[q] = fmaf(w4.z, v4.z, acc[q]);
        acc[q] = fmaf(w4.w, v4.w, acc[q]);
      }
    }
    // deep prefetch: emb for step it+1 (from xv), x for step it+2
    ev = *(const float2*)(embed + (size_t)xv * EMB + e1);
    {
      int sn = it + 2 < SLEN ? it + 2 : SLEN - 1;
      xv = x[(b0 + b1) * SLEN + (dir ? (SLEN - 1 - sn) : sn)];
    }
    const int keb = kg * 16;
#pragma unroll
    for (int c = 0; c < 4; ++c) {
      float4 w4 = wreg[8 + c];
#pragma unroll
      for (int q = 0; q < BQ; ++q) {
        float4 v4 = *(const float4*)&vemb[q][keb + c * 4]; // broadcast read
        acc[q] = fmaf(w4.x, v4.x, acc[q]);
        acc[q] = fmaf(w4.y, v4.y, acc[q]);
        acc[q] = fmaf(w4.z, v4.z, acc[q]);
        acc[q] = fmaf(w4.w, v4.w, acc[q]);
      }
    }

    // ---- 5. write K-partials: redl[kg][b][u][gate] -----------------------
    {
      const int rbase = kg * 512 + uo * 4 + gi;
#pragma unroll
      for (int q = 0; q < BQ; ++q) redl[rbase + q * 64] = acc[q];
    }
    __syncthreads();                                   // SYNC_B

    // ---- 6. gates + state + h publish + counter (wave0 only) -------------
    if (tid < 64) {
      const int u = tid & 15;
      const float4 bb = *(const float4*)&biasf[u][0];
#pragma unroll
      for (int pp = 0; pp < 2; ++pp) {
        const int b = (tid >> 4) + pp * 4;
        float s0 = bb.x, s1 = bb.y, s2 = bb.z, s3 = bb.w;
#pragma unroll
        for (int k2 = 0; k2 < 8; ++k2) {
          const float4 r4 = *(const float4*)&redl[k2 * 512 + b * 64 + u * 4];
          s0 += r4.x; s1 += r4.y; s2 += r4.z; s3 += r4.w;
        }
        float ig = sigmoidf_(s0);
        float fg = sigmoidf_(s1);
        float gv = tanhf(s2);
        float og = sigmoidf_(s3);
        float cv = fg * cst[b][u] + ig * gv;
        cst[b][u] = cv;
        float hv = og * tanhf(cv);
        __hip_atomic_store(h_hist + ((size_t)(dir * SLEN + t) * BATCH + (b0 + b)) * HID
                             + rk * 16 + u,
                           hv, __ATOMIC_RELAXED, __HIP_MEMORY_SCOPE_AGENT);
      }
      asm volatile("s_waitcnt vmcnt(0)" ::: "memory");   // h committed
      if (tid == 0)
        __hip_atomic_fetch_add(cnt + (size_t)g * SLEN + it, 1u,
                               __ATOMIC_RELAXED, __HIP_MEMORY_SCOPE_AGENT);
    }
    // no trailing barrier: next-iter SYNC_A + poll provide ordering.
  }
}

// ---------------------------------------------------------------------------
// feats[s][b][tag] = [hf|hb] . Wc[tag] + bc[tag]
// grid = (512/4)*8 blocks (4 timesteps, 8-batch chunk), 256 threads.
// Wc staged once per block, reused for 4 timesteps.
// ---------------------------------------------------------------------------
__global__ __launch_bounds__(256) void feats_kernel(
    const float* __restrict__ h_hist, const float* __restrict__ Wc,
    const float* __restrict__ bc, float* __restrict__ feats)
{
  const int s0  = (blockIdx.x >> 3) * SB;
  const int b0  = (blockIdx.x & 7) * FB;
  const int tid = threadIdx.x;
  __shared__ float wc[NT * 516];    // 37.2 KB
  __shared__ float hl[FB * 516];    // 16.5 KB
  __shared__ float bcl[NT];
  if (tid < NT) bcl[tid] = bc[tid];
  for (int f = tid * 4; f < NT * 512; f += 1024) {
    float4 v = *(const float4*)(Wc + f);
    *(float4*)&wc[(f >> 9) * 516 + (f & 511)] = v;
  }
  for (int si = 0; si < SB; ++si) {
    const int s = s0 + si;
    const float* src0 = h_hist + ((size_t)s * BATCH + b0) * HID;
    const float* src1 = h_hist + ((size_t)(SLEN + s) * BATCH + b0) * HID;
    for (int f = tid * 4; f < FB * 256; f += 1024) {
      int b = f >> 8, j = f & 255;
      *(float4*)&hl[b * 516 + j]       = *(const float4*)(src0 + f);
      *(float4*)&hl[b * 516 + 256 + j] = *(const float4*)(src1 + f);
    }
    __syncthreads();
    if (tid < FB * NT) {
      int b = tid / NT, tag = tid - b * NT;
      float a = bcl[tag];
      const float* hp = &hl[b * 516];
      const float* wp = &wc[tag * 516];
#pragma unroll 8
      for (int k = 0; k < 512; k += 4) {
        float4 h4 = *(const float4*)(hp + k);
        float4 w4 = *(const float4*)(wp + k);
        a = fmaf(h4.x, w4.x, a); a = fmaf(h4.y, w4.y, a);
        a = fmaf(h4.z, w4.z, a); a = fmaf(h4.w, w4.w, a);
      }
      feats[((size_t)s * BATCH + b0 + b) * NT + tag] = a;
    }
    __syncthreads();   // WAR guard before restaging hl
  }
}

// ---------------------------------------------------------------------------
// Viterbi + backtrace, one block per batch, 64 threads (lanes 0..17 active).
// Replicates reference exactly, including add order:
//   cur = (feats[to] + trans[from][to]) + partition[from];  new_p = max(cur)
// strict > keeps the FIRST max (matches jnp.argmax). Masked bp=0, snapshot at
// t=len-1, back[len-1]=pointer overwrite, decode[S-1]=pointer.
// ---------------------------------------------------------------------------
__global__ __launch_bounds__(64) void viterbi_kernel(
    const float* __restrict__ feats, const int* __restrict__ mask,
    const float* __restrict__ trans, float* __restrict__ out)
{
  const int b = blockIdx.x;
  const int lane = threadIdx.x;
  __shared__ float tr[NT][NT + 1];
  __shared__ float part[2][NT + 2];
  __shared__ float lastp[NT + 2];
  __shared__ unsigned char bp[SLEN][20];
  __shared__ int len_s;

  for (int f = lane; f < NT * NT; f += 64) tr[f / NT][f % NT] = trans[f];
  int m = 0;
#pragma unroll
  for (int i = 0; i < 8; ++i) m += mask[b * SLEN + lane * 8 + i];
  for (int off = 32; off; off >>= 1) m += __shfl_down(m, off);
  if (lane == 0) len_s = m;
  __syncthreads();
  const int len = len_s;

  if (lane < NT) part[0][lane] = feats[(size_t)b * NT + lane] + tr[16][lane];  // START=16
  __syncthreads();

  int cur = 0;
  float fnext = (lane < NT) ? feats[((size_t)BATCH + b) * NT + lane] : 0.0f;
  int   mnext = mask[b * SLEN + 1];
  for (int t = 1; t < SLEN; ++t) {
    float fcur = fnext; int mcur = mnext;
    if (t < SLEN - 1) {
      fnext = (lane < NT) ? feats[((size_t)(t + 1) * BATCH + b) * NT + lane] : 0.0f;
      mnext = mask[b * SLEN + t + 1];
    }
    if (lane < NT) {
      float best = -3.0e38f; int bf = 0;
#pragma unroll
      for (int from = 0; from < NT; ++from) {
        float v = (fcur + tr[from][lane]) + part[cur][from];  // exact ref order
        if (v > best) { best = v; bf = from; }
      }
      part[cur ^ 1][lane] = best;          // new_p includes feats (ref semantics)
      bp[t][lane] = mcur ? (unsigned char)bf : (unsigned char)0;
      if (t == len - 1) lastp[lane] = best;
    }
    cur ^= 1;
    __syncthreads();
  }

  if (lane == 0) {
    float best = -3.0e38f; int bf = 0;
    for (int from = 0; from < NT; ++from) {
      float v = lastp[from] + tr[from][17];      // END=17
      if (v > best) { best = v; bf = from; }
    }
    out[b] = best;                                // path_score
    int ptr = bf;
    out[BATCH + (size_t)b * SLEN + (SLEN - 1)] = (float)ptr;
    for (int i = SLEN - 2; i >= 0; --i) {
      int nw = (i == len - 1) ? bf : (int)bp[i + 1][ptr];
      out[BATCH + (size_t)b * SLEN + i] = (float)nw;
      ptr = nw;
    }
  }
}

// ---------------------------------------------------------------------------
extern "C" void kernel_launch(void* const* d_in, const int* in_sizes, int n_in,
                              void* d_out, int out_size, void* d_ws, size_t ws_size,
                              hipStream_t stream) {
  const int*   x      = (const int*)  d_in[0];
  const int*   mask   = (const int*)  d_in[1];
  const float* embed  = (const float*)d_in[2];
  const float* Wih_f  = (const float*)d_in[3];
  const float* Whh_f  = (const float*)d_in[4];
  const float* bih_f  = (const float*)d_in[5];
  const float* bhh_f  = (const float*)d_in[6];
  const float* Wih_b  = (const float*)d_in[7];
  const float* Whh_b  = (const float*)d_in[8];
  const float* bih_b  = (const float*)d_in[9];
  const float* bhh_b  = (const float*)d_in[10];
  const float* Wc     = (const float*)d_in[11];
  const float* bc     = (const float*)d_in[12];
  const float* trans  = (const float*)d_in[13];
  const float* h0     = (const float*)d_in[14];
  const float* c0     = (const float*)d_in[15];
  float* out = (float*)d_out;

  // ws layout: h_hist @0 (64MB); cnt and feats SHARE ws+64MB (disjoint in
  // time: cnt used only during lstm, feats written only after lstm; cnt
  // re-zeroed each launch -> graph-replay deterministic).
  char* ws = (char*)d_ws;
  float* h_hist = (float*)ws;                                 // 64 MB
  u32*   cnt    = (u32*)(ws + (size_t)67108864);              // 32 KB
  float* feats  = (float*)(ws + (size_t)67108864);            // 2.25 MB (aliases cnt)

  hipMemsetAsync(cnt, 0, (size_t)NGROUP * SLEN * sizeof(u32), stream);
  lstm_kernel<<<256, 512, 0, stream>>>(x, embed, Wih_f, Whh_f, bih_f, bhh_f,
                                       Wih_b, Whh_b, bih_b, bhh_b, h0, c0,
                                       h_hist, cnt);
  feats_kernel<<<(SLEN / SB) * 8, 256, 0, stream>>>(h_hist, Wc, bc, feats);
  viterbi_kernel<<<BATCH, 64, 0, stream>>>(feats, mask, trans, out);
}